// Round 1
// baseline (974.168 us; speedup 1.0000x reference)
//
#include <hip/hip_runtime.h>

#define NLVL 16
#define T_MASK ((1u << 19) - 1)
#define PTS_PER_BLOCK 16   // 256 threads / 16 levels

__constant__ int c_res[NLVL] = {16, 20, 25, 32, 40, 50, 64, 80,
                                101, 128, 161, 203, 256, 322, 406, 512};
__constant__ int c_off[NLVL] = {0, 4913, 14174, 31750, 67687, 136608, 269259, 543884,
                                1075325, 1599613, 2123901, 2648189, 3172477, 3696765, 4221053, 4745341};
__constant__ float c_grid[NLVL] = {
    (float)(2.0 / 16.0),  (float)(2.0 / 20.0),  (float)(2.0 / 25.0),  (float)(2.0 / 32.0),
    (float)(2.0 / 40.0),  (float)(2.0 / 50.0),  (float)(2.0 / 64.0),  (float)(2.0 / 80.0),
    (float)(2.0 / 101.0), (float)(2.0 / 128.0), (float)(2.0 / 161.0), (float)(2.0 / 203.0),
    (float)(2.0 / 256.0), (float)(2.0 / 322.0), (float)(2.0 / 406.0), (float)(2.0 / 512.0)};

__global__ __launch_bounds__(256) void hashgrid_fwd(const float* __restrict__ x,
                                                    const float* __restrict__ tables,
                                                    float* __restrict__ out,
                                                    int n_points) {
    __shared__ float sx[PTS_PER_BLOCK * 3];
    const int p0 = blockIdx.x * PTS_PER_BLOCK;
    if (threadIdx.x < PTS_PER_BLOCK * 3) {
        int gi = p0 * 3 + (int)threadIdx.x;
        sx[threadIdx.x] = (gi < n_points * 3) ? x[gi] : 0.0f;
    }
    __syncthreads();

    const int t = blockIdx.x * 256 + (int)threadIdx.x;
    const int p = t >> 4;
    if (p >= n_points) return;
    const int l = t & 15;
    const int lp = (int)(threadIdx.x >> 4);

    const float xx = sx[lp * 3 + 0];
    const float xy = sx[lp * 3 + 1];
    const float xz = sx[lp * 3 + 2];

    const int res = c_res[l];
    const float grid = c_grid[l];
    const float2* __restrict__ tab = reinterpret_cast<const float2*>(tables) + c_off[l];

    // Per-dimension base cell + interpolation weight, float32 exactly as reference.
    int bx, by, bz;
    float wx, wy, wz;
    {
        float xc = fminf(fmaxf(xx, -1.0f), 1.0f);
        float fb = floorf((xc + 1.0f) / grid);
        bx = (int)fb;
        float vmin = fb * grid - 1.0f;
        wx = (xx - vmin) / grid;
    }
    {
        float xc = fminf(fmaxf(xy, -1.0f), 1.0f);
        float fb = floorf((xc + 1.0f) / grid);
        by = (int)fb;
        float vmin = fb * grid - 1.0f;
        wy = (xy - vmin) / grid;
    }
    {
        float xc = fminf(fmaxf(xz, -1.0f), 1.0f);
        float fb = floorf((xc + 1.0f) / grid);
        bz = (int)fb;
        float vmin = fb * grid - 1.0f;
        wz = (xz - vmin) / grid;
    }

    float2 e0, e1, e2, e3, e4, e5, e6, e7;
    if (l < 8) {
        // dense levels: idx = cx*res^2 + cy*res + cz (reference's aliased strides)
        const int r2 = res * res;
        const int base = bx * r2 + by * res + bz;
        e0 = tab[base];
        e1 = tab[base + 1];
        e2 = tab[base + res];
        e3 = tab[base + res + 1];
        e4 = tab[base + r2];
        e5 = tab[base + r2 + 1];
        e6 = tab[base + r2 + res];
        e7 = tab[base + r2 + res + 1];
    } else {
        // hashed levels: h = cx*1 ^ cy*2654435761 ^ cz*805459861, idx = h & (T-1)
        const unsigned int hx0 = (unsigned int)bx;
        const unsigned int hx1 = (unsigned int)(bx + 1);
        const unsigned int hy0 = (unsigned int)by * 2654435761u;
        const unsigned int hy1 = (unsigned int)(by + 1) * 2654435761u;
        const unsigned int hz0 = (unsigned int)bz * 805459861u;
        const unsigned int hz1 = (unsigned int)(bz + 1) * 805459861u;
        e0 = tab[(hx0 ^ hy0 ^ hz0) & T_MASK];
        e1 = tab[(hx0 ^ hy0 ^ hz1) & T_MASK];
        e2 = tab[(hx0 ^ hy1 ^ hz0) & T_MASK];
        e3 = tab[(hx0 ^ hy1 ^ hz1) & T_MASK];
        e4 = tab[(hx1 ^ hy0 ^ hz0) & T_MASK];
        e5 = tab[(hx1 ^ hy0 ^ hz1) & T_MASK];
        e6 = tab[(hx1 ^ hy1 ^ hz0) & T_MASK];
        e7 = tab[(hx1 ^ hy1 ^ hz1) & T_MASK];
    }

    // Trilinear: corner order (i=x)*4 + (j=y)*2 + (k=z)
    const float ox = 1.0f - wx, oy = 1.0f - wy, oz = 1.0f - wz;
    float c00x = e0.x * ox + e4.x * wx, c00y = e0.y * ox + e4.y * wx;
    float c01x = e1.x * ox + e5.x * wx, c01y = e1.y * ox + e5.y * wx;
    float c10x = e2.x * ox + e6.x * wx, c10y = e2.y * ox + e6.y * wx;
    float c11x = e3.x * ox + e7.x * wx, c11y = e3.y * ox + e7.y * wx;
    float c0x = c00x * oy + c10x * wy, c0y = c00y * oy + c10y * wy;
    float c1x = c01x * oy + c11x * wy, c1y = c01y * oy + c11y * wy;
    float2 r;
    r.x = c0x * oz + c1x * wz;
    r.y = c0y * oz + c1y * wz;

    reinterpret_cast<float2*>(out)[p * NLVL + l] = r;
}

extern "C" void kernel_launch(void* const* d_in, const int* in_sizes, int n_in,
                              void* d_out, int out_size, void* d_ws, size_t ws_size,
                              hipStream_t stream) {
    const float* x = (const float*)d_in[0];
    const float* tables = (const float*)d_in[1];
    float* out = (float*)d_out;
    const int n_points = in_sizes[0] / 3;

    const int blocks = (n_points + PTS_PER_BLOCK - 1) / PTS_PER_BLOCK;
    hipLaunchKernelGGL(hashgrid_fwd, dim3(blocks), dim3(256), 0, stream, x, tables, out, n_points);
}

// Round 2
// 718.022 us; speedup vs baseline: 1.3567x; 1.3567x over previous
//
#include <hip/hip_runtime.h>

#define NLVL 16
#define T_MASK ((1u << 19) - 1)
#define CHUNK 256

typedef float v2f __attribute__((ext_vector_type(2)));

__constant__ int c_res[NLVL] = {16, 20, 25, 32, 40, 50, 64, 80,
                                101, 128, 161, 203, 256, 322, 406, 512};
__constant__ int c_off[NLVL] = {0, 4913, 14174, 31750, 67687, 136608, 269259, 543884,
                                1075325, 1599613, 2123901, 2648189, 3172477, 3696765, 4221053, 4745341};
__constant__ float c_grid[NLVL] = {
    (float)(2.0 / 16.0),  (float)(2.0 / 20.0),  (float)(2.0 / 25.0),  (float)(2.0 / 32.0),
    (float)(2.0 / 40.0),  (float)(2.0 / 50.0),  (float)(2.0 / 64.0),  (float)(2.0 / 80.0),
    (float)(2.0 / 101.0), (float)(2.0 / 128.0), (float)(2.0 / 161.0), (float)(2.0 / 203.0),
    (float)(2.0 / 256.0), (float)(2.0 / 322.0), (float)(2.0 / 406.0), (float)(2.0 / 512.0)};

__device__ __forceinline__ void dim_setup(float xv, float grid, int& b, float& w) {
    float xc = fminf(fmaxf(xv, -1.0f), 1.0f);
    float fb = floorf((xc + 1.0f) / grid);
    b = (int)fb;
    float vmin = fb * grid - 1.0f;
    w = (xv - vmin) / grid;
}

// Kernel A: one block = one level x 256 points. level = blockIdx & 15 so all
// blocks of level l land on XCD (l&7) under round-robin dispatch -> the 4 MB
// hashed table per level becomes L2-resident on its XCD.
__global__ __launch_bounds__(256) void gather_level(const float* __restrict__ x,
                                                    const float* __restrict__ tables,
                                                    v2f* __restrict__ ws,
                                                    int n_points) {
    __shared__ float sx[CHUNK * 3];
    const int level = (int)(blockIdx.x & 15);
    const int chunk = (int)(blockIdx.x >> 4);
    const int p0 = chunk * CHUNK;

    for (int i = (int)threadIdx.x; i < CHUNK * 3; i += 256) {
        int gi = p0 * 3 + i;
        sx[i] = (gi < n_points * 3) ? x[gi] : 0.0f;
    }
    __syncthreads();

    const int p = p0 + (int)threadIdx.x;
    if (p >= n_points) return;

    const float xx = sx[threadIdx.x * 3 + 0];
    const float xy = sx[threadIdx.x * 3 + 1];
    const float xz = sx[threadIdx.x * 3 + 2];

    const int res = c_res[level];
    const float grid = c_grid[level];
    const v2f* __restrict__ tab = reinterpret_cast<const v2f*>(tables) + c_off[level];

    int bx, by, bz;
    float wx, wy, wz;
    dim_setup(xx, grid, bx, wx);
    dim_setup(xy, grid, by, wy);
    dim_setup(xz, grid, bz, wz);

    v2f e0, e1, e2, e3, e4, e5, e6, e7;
    if (level < 8) {   // block-uniform branch
        const int r2 = res * res;
        const int base = bx * r2 + by * res + bz;
        e0 = tab[base];
        e1 = tab[base + 1];
        e2 = tab[base + res];
        e3 = tab[base + res + 1];
        e4 = tab[base + r2];
        e5 = tab[base + r2 + 1];
        e6 = tab[base + r2 + res];
        e7 = tab[base + r2 + res + 1];
    } else {
        const unsigned int hx0 = (unsigned int)bx;
        const unsigned int hx1 = (unsigned int)(bx + 1);
        const unsigned int hy0 = (unsigned int)by * 2654435761u;
        const unsigned int hy1 = (unsigned int)(by + 1) * 2654435761u;
        const unsigned int hz0 = (unsigned int)bz * 805459861u;
        const unsigned int hz1 = (unsigned int)(bz + 1) * 805459861u;
        e0 = tab[(hx0 ^ hy0 ^ hz0) & T_MASK];
        e1 = tab[(hx0 ^ hy0 ^ hz1) & T_MASK];
        e2 = tab[(hx0 ^ hy1 ^ hz0) & T_MASK];
        e3 = tab[(hx0 ^ hy1 ^ hz1) & T_MASK];
        e4 = tab[(hx1 ^ hy0 ^ hz0) & T_MASK];
        e5 = tab[(hx1 ^ hy0 ^ hz1) & T_MASK];
        e6 = tab[(hx1 ^ hy1 ^ hz0) & T_MASK];
        e7 = tab[(hx1 ^ hy1 ^ hz1) & T_MASK];
    }

    const float ox = 1.0f - wx, oy = 1.0f - wy, oz = 1.0f - wz;
    v2f c00 = e0 * ox + e4 * wx;
    v2f c01 = e1 * ox + e5 * wx;
    v2f c10 = e2 * ox + e6 * wx;
    v2f c11 = e3 * ox + e7 * wx;
    v2f c0 = c00 * oy + c10 * wy;
    v2f c1 = c01 * oy + c11 * wy;
    v2f r = c0 * oz + c1 * wz;

    // coalesced [level][point] store; nontemporal so it doesn't evict the table
    __builtin_nontemporal_store(r, &ws[(size_t)level * n_points + p]);
}

// Kernel B: transpose ws [level][point] -> out [point][level] via LDS tile.
__global__ __launch_bounds__(256) void transpose_pl(const v2f* __restrict__ ws,
                                                    v2f* __restrict__ out,
                                                    int n_points) {
    __shared__ v2f tile[NLVL][257];   // 257 pad -> conflict-free scattered reads
    const int p0 = (int)blockIdx.x * CHUNK;
    const int tid = (int)threadIdx.x;

    for (int l = 0; l < NLVL; ++l) {
        int p = p0 + tid;
        if (p < n_points)
            tile[l][tid] = __builtin_nontemporal_load(&ws[(size_t)l * n_points + p]);
    }
    __syncthreads();

    for (int k = 0; k < NLVL; ++k) {
        int i = k * 256 + tid;           // flat v2f index within this block's out span
        int pl = i >> 4;
        int l = i & 15;
        if (p0 + pl < n_points)
            __builtin_nontemporal_store(tile[l][pl], &out[(size_t)p0 * NLVL + i]);
    }
}

// Fallback (ws too small): round-0 direct kernel, point-major threads.
__global__ __launch_bounds__(256) void hashgrid_direct(const float* __restrict__ x,
                                                       const float* __restrict__ tables,
                                                       float* __restrict__ out,
                                                       int n_points) {
    const int t = (int)blockIdx.x * 256 + (int)threadIdx.x;
    const int p = t >> 4;
    if (p >= n_points) return;
    const int l = t & 15;

    const float xx = x[p * 3 + 0];
    const float xy = x[p * 3 + 1];
    const float xz = x[p * 3 + 2];

    const int res = c_res[l];
    const float grid = c_grid[l];
    const v2f* __restrict__ tab = reinterpret_cast<const v2f*>(tables) + c_off[l];

    int bx, by, bz;
    float wx, wy, wz;
    dim_setup(xx, grid, bx, wx);
    dim_setup(xy, grid, by, wy);
    dim_setup(xz, grid, bz, wz);

    v2f e0, e1, e2, e3, e4, e5, e6, e7;
    if (l < 8) {
        const int r2 = res * res;
        const int base = bx * r2 + by * res + bz;
        e0 = tab[base];       e1 = tab[base + 1];
        e2 = tab[base + res]; e3 = tab[base + res + 1];
        e4 = tab[base + r2];  e5 = tab[base + r2 + 1];
        e6 = tab[base + r2 + res]; e7 = tab[base + r2 + res + 1];
    } else {
        const unsigned int hx0 = (unsigned int)bx, hx1 = (unsigned int)(bx + 1);
        const unsigned int hy0 = (unsigned int)by * 2654435761u;
        const unsigned int hy1 = (unsigned int)(by + 1) * 2654435761u;
        const unsigned int hz0 = (unsigned int)bz * 805459861u;
        const unsigned int hz1 = (unsigned int)(bz + 1) * 805459861u;
        e0 = tab[(hx0 ^ hy0 ^ hz0) & T_MASK];
        e1 = tab[(hx0 ^ hy0 ^ hz1) & T_MASK];
        e2 = tab[(hx0 ^ hy1 ^ hz0) & T_MASK];
        e3 = tab[(hx0 ^ hy1 ^ hz1) & T_MASK];
        e4 = tab[(hx1 ^ hy0 ^ hz0) & T_MASK];
        e5 = tab[(hx1 ^ hy0 ^ hz1) & T_MASK];
        e6 = tab[(hx1 ^ hy1 ^ hz0) & T_MASK];
        e7 = tab[(hx1 ^ hy1 ^ hz1) & T_MASK];
    }

    const float ox = 1.0f - wx, oy = 1.0f - wy, oz = 1.0f - wz;
    v2f c00 = e0 * ox + e4 * wx;
    v2f c01 = e1 * ox + e5 * wx;
    v2f c10 = e2 * ox + e6 * wx;
    v2f c11 = e3 * ox + e7 * wx;
    v2f c0 = c00 * oy + c10 * wy;
    v2f c1 = c01 * oy + c11 * wy;
    v2f r = c0 * oz + c1 * wz;
    reinterpret_cast<v2f*>(out)[(size_t)p * NLVL + l] = r;
}

extern "C" void kernel_launch(void* const* d_in, const int* in_sizes, int n_in,
                              void* d_out, int out_size, void* d_ws, size_t ws_size,
                              hipStream_t stream) {
    const float* x = (const float*)d_in[0];
    const float* tables = (const float*)d_in[1];
    float* out = (float*)d_out;
    const int n_points = in_sizes[0] / 3;

    const size_t ws_needed = (size_t)n_points * NLVL * sizeof(v2f);
    const int chunks = (n_points + CHUNK - 1) / CHUNK;

    if (ws_size >= ws_needed) {
        hipLaunchKernelGGL(gather_level, dim3(chunks * NLVL), dim3(256), 0, stream,
                           x, tables, (v2f*)d_ws, n_points);
        hipLaunchKernelGGL(transpose_pl, dim3(chunks), dim3(256), 0, stream,
                           (v2f*)d_ws, (v2f*)out, n_points);
    } else {
        const int blocks = (n_points * NLVL + 255) / 256;
        hipLaunchKernelGGL(hashgrid_direct, dim3(blocks), dim3(256), 0, stream,
                           x, tables, out, n_points);
    }
}